// Round 14
// baseline (279.285 us; speedup 1.0000x reference)
//
#include <hip/hip_runtime.h>
#include <cmath>

#define MAXV 8

// ---------------------------------------------------------------------------
// Kernel 1: cost matrices for the RECTANGULAR problem (no padding).
//   Ct[b][n][m]  = score_cost + giou_cost   (transposed cost, coalesced rows)
//   boxc[b][m][n] = giou_cost
// Math mirrors the reference f32 op order exactly.
// ---------------------------------------------------------------------------
__global__ __launch_bounds__(256) void cost_kernel(
    const float* __restrict__ p_box, const float* __restrict__ p_score,
    const float* __restrict__ t_box, const float* __restrict__ t_score,
    float* __restrict__ Ct, float* __restrict__ boxc,
    int B, int M, int N)
{
    int g = blockIdx.x * 256 + threadIdx.x;
    int total = B * M * N;
    if (g >= total) return;
    int b = g / (M * N);
    int rem = g - b * M * N;
    int n = rem / M;
    int m = rem - n * M;

    const float* bp = p_box + ((size_t)b * M + m) * 5;
    const float* bt = t_box + ((size_t)b * N + n) * 5;
    float pcx = bp[0], pcy = bp[1], pw = bp[2], ph = bp[3], pth = bp[4];
    float tcx = bt[0], tcy = bt[1], tw = bt[2], th = bt[3], tth = bt[4];

    float pc = cosf(pth), ps = sinf(pth);
    float tc = cosf(tth), ts = sinf(tth);

    const float DX[4] = {-0.5f, 0.5f, 0.5f, -0.5f};
    const float DY[4] = {-0.5f, -0.5f, 0.5f, 0.5f};
    float cpx[4], cpy[4], ctx[4], cty[4];
#pragma unroll
    for (int k = 0; k < 4; k++) {
        float dx = DX[k] * pw, dy = DY[k] * ph;
        cpx[k] = pcx + dx * pc - dy * ps;
        cpy[k] = pcy + dx * ps + dy * pc;
        float dx2 = DX[k] * tw, dy2 = DY[k] * th;
        ctx[k] = tcx + dx2 * tc - dy2 * ts;
        cty[k] = tcy + dx2 * ts + dy2 * tc;
    }

    float px[MAXV], py[MAXV];
#pragma unroll
    for (int k = 0; k < MAXV; k++) {
        px[k] = (k < 4) ? cpx[k] : 0.0f;
        py[k] = (k < 4) ? cpy[k] : 0.0f;
    }
    int cnt = 4;

#pragma unroll
    for (int e = 0; e < 4; e++) {
        float ax = ctx[e], ay = cty[e];
        float bx2 = ctx[(e + 1) & 3], by2 = cty[(e + 1) & 3];
        float dx = bx2 - ax, dy = by2 - ay;
        float qx[MAXV], qy[MAXV];
#pragma unroll
        for (int k = 0; k < MAXV; k++) { qx[k] = 0.0f; qy[k] = 0.0f; }
        int nc = 0;
#pragma unroll
        for (int i = 0; i < MAXV; i++) {
            if (i < cnt) {
                bool wrap = !(i + 1 < cnt);
                float nx = wrap ? px[0] : px[(i + 1) & 7];
                float ny = wrap ? py[0] : py[(i + 1) & 7];
                float sc = dx * (py[i] - ay) - dy * (px[i] - ax);
                float sn = dx * (ny - ay) - dy * (nx - ax);
                bool inc = (sc >= 0.0f), inn = (sn >= 0.0f);
                float den = sc - sn;
                if (!(fabsf(den) > 1e-9f)) den = 1e-9f;
                float t = sc / den;
                float ix = px[i] + t * (nx - px[i]);
                float iy = py[i] + t * (ny - py[i]);
                if (inc) {
                    if (nc < MAXV) { qx[nc] = px[i]; qy[nc] = py[i]; }
                    nc++;
                }
                if (inc != inn) {
                    if (nc < MAXV) { qx[nc] = ix; qy[nc] = iy; }
                    nc++;
                }
            }
        }
        cnt = (nc > MAXV) ? MAXV : nc;
#pragma unroll
        for (int k = 0; k < MAXV; k++) {
            px[k] = (k < cnt) ? qx[k] : 0.0f;
            py[k] = (k < cnt) ? qy[k] : 0.0f;
        }
    }

    float a2 = 0.0f;
#pragma unroll
    for (int i = 0; i < MAXV; i++) {
        if (i < cnt) {
            bool wrap = !(i + 1 < cnt);
            float nx = wrap ? px[0] : px[(i + 1) & 7];
            float ny = wrap ? py[0] : py[(i + 1) & 7];
            a2 += px[i] * ny - nx * py[i];
        }
    }
    float inter = 0.5f * fabsf(a2);

    float uni = tw * th + pw * ph - inter;

    float xmin = ctx[0], xmax = ctx[0], ymin = cty[0], ymax = cty[0];
#pragma unroll
    for (int k = 1; k < 4; k++) {
        xmin = fminf(xmin, ctx[k]); xmax = fmaxf(xmax, ctx[k]);
        ymin = fminf(ymin, cty[k]); ymax = fmaxf(ymax, cty[k]);
    }
#pragma unroll
    for (int k = 0; k < 4; k++) {
        xmin = fminf(xmin, cpx[k]); xmax = fmaxf(xmax, cpx[k]);
        ymin = fminf(ymin, cpy[k]); ymax = fmaxf(ymax, cpy[k]);
    }
    float enc = (xmax - xmin) * (ymax - ymin);

    float giou = inter / uni - (enc - uni) / enc;
    float bc = 1.0f - giou;
    float scst = fmaxf(0.0f, t_score[b * N + n] - p_score[b * M + m]);

    Ct[((size_t)b * N + n) * M + m] = scst + bc;
    boxc[((size_t)b * M + m) * N + n] = bc;
}

// ---------------------------------------------------------------------------
// Kernel 1.5: per-target-row min over the M pred columns (u init, f32 exact).
// ---------------------------------------------------------------------------
__global__ __launch_bounds__(64) void rowmin_kernel(
    const float* __restrict__ Ct, float* __restrict__ rmv, int M)
{
    int bt = blockIdx.x;
    int lane = threadIdx.x;
    const float* row = Ct + (size_t)bt * M;

    float bv = 1e30f;
    for (int c = 4 * lane; c < M; c += 256) {
        float4 v = *reinterpret_cast<const float4*>(row + c);
        bv = fminf(bv, fminf(fminf(v.x, v.y), fminf(v.z, v.w)));
    }
#pragma unroll
    for (int off = 1; off < 64; off <<= 1)
        bv = fminf(bv, __shfl_xor(bv, off, 64));
    if (lane == 0) rmv[bt] = bv;
}

// ---------------------------------------------------------------------------
// Kernel 1.6: per-column (min, first argmin row) of the u-reduced matrix,
// computed in f64 so v is EXACT (C and u are f32 -> C-u exact in f64).
// ---------------------------------------------------------------------------
__global__ __launch_bounds__(256) void colmin_kernel(
    const float* __restrict__ Ct, const float* __restrict__ rmv,
    double* __restrict__ vmin, int* __restrict__ varg, int M, int N)
{
    int b = blockIdx.x;
    const float* Cb = Ct + (size_t)b * N * M;
    const float* rb = rmv + (size_t)b * N;
    for (int j = threadIdx.x; j < M; j += blockDim.x) {
        double bv = 1e30; int bt = 0;
        for (int t = 0; t < N; ++t) {
            double val = (double)Cb[(size_t)t * M + j] - (double)rb[t];
            if (val < bv) { bv = val; bt = t; }
        }
        vmin[(size_t)b * M + j] = bv;
        varg[(size_t)b * M + j] = bt + 1;   // 1-based target
    }
}

// ---------------------------------------------------------------------------
// Kernel 2: identical ALGORITHM to round 13 (f64 duals, replacement-form
// transfer, ARR with strict/zero-cost displacement, exact Dijkstra tail) —
// round 13 passed — plus two LATENCY-ONLY changes:
//  (a) ARR prefetches the continuation row (displaced k or next queue entry)
//      before the update tail, hiding the ~200cy L2 row-load latency;
//  (b) Dijkstra prefetches the NEXT phase's (row, u) at the START of each
//      phase (provably untouched during the phase: tree rows are matched
//      targets; the next deferred target is unmatched).
// No arithmetic/order change => identical matching => identical absmax.
// ---------------------------------------------------------------------------
__device__ __forceinline__ int sel4(int a0, int a1, int a2, int a3, int s) {
    return s == 0 ? a0 : (s == 1 ? a1 : (s == 2 ? a2 : a3));
}

// f64 val = fmin(val, dpp_neighbor(val)); invalid lanes contribute +inf.
#define DPP_FMIN64_STAGE(val, CTRL) do {                                      \
    long long _bits = __double_as_longlong(val);                              \
    int _lo = __builtin_amdgcn_update_dpp(0, (int)_bits,                      \
                                          CTRL, 0xf, 0xf, false);             \
    int _hi = __builtin_amdgcn_update_dpp(0x7FF00000, (int)(_bits >> 32),     \
                                          CTRL, 0xf, 0xf, false);             \
    double _o = __longlong_as_double(                                         \
        ((long long)_hi << 32) | (unsigned)_lo);                              \
    (val) = fmin((val), _o);                                                  \
} while (0)

// f64 paired (min1,min2) stage; disjoint lane-set combine.
#define DPP_PAIR64_STAGE(g1, g2, CTRL) do {                                   \
    long long _b1 = __double_as_longlong(g1);                                 \
    long long _b2 = __double_as_longlong(g2);                                 \
    int _l1 = __builtin_amdgcn_update_dpp(0, (int)_b1, CTRL, 0xf, 0xf, false);\
    int _h1 = __builtin_amdgcn_update_dpp(0x7FF00000, (int)(_b1 >> 32),       \
                                          CTRL, 0xf, 0xf, false);             \
    int _l2 = __builtin_amdgcn_update_dpp(0, (int)_b2, CTRL, 0xf, 0xf, false);\
    int _h2 = __builtin_amdgcn_update_dpp(0x7FF00000, (int)(_b2 >> 32),       \
                                          CTRL, 0xf, 0xf, false);             \
    double _o1 = __longlong_as_double(((long long)_h1 << 32) | (unsigned)_l1);\
    double _o2 = __longlong_as_double(((long long)_h2 << 32) | (unsigned)_l2);\
    double _n2 = fmin(fmax((g1), _o1), fmin((g2), _o2));                      \
    (g1) = fmin((g1), _o1);                                                   \
    (g2) = _n2;                                                               \
} while (0)

__device__ __forceinline__ double readlane_f64(double v, int lane) {
    long long b = __double_as_longlong(v);
    int lo = __builtin_amdgcn_readlane((int)b, lane);
    int hi = __builtin_amdgcn_readlane((int)(b >> 32), lane);
    return __longlong_as_double(((long long)hi << 32) | (unsigned)lo);
}

__global__ __launch_bounds__(64) void hungarian_rect(
    const float* __restrict__ Ct, const float* __restrict__ boxc,
    const float* __restrict__ p_score, const float* __restrict__ t_score,
    const float* __restrict__ rmv, const double* __restrict__ vmin,
    const int* __restrict__ varg,
    float* __restrict__ out, int B, int M, int N)
{
    const double DINF = 1e30;
    const int IINF = 0x7fffffff;
    int b = blockIdx.x;
    int lane = threadIdx.x;
    const float* C = Ct + (size_t)b * N * M;   // [N][M] rows contiguous

    __shared__ double u[257];                  // dual u, target 1..N
    __shared__ double v_lds[256];              // v for transfer scans
    __shared__ double tmin[257];               // transfer new-u per matched row
    __shared__ int claim[257];                 // row -> owning column
    __shared__ int ulist[257];                 // rows for ARR
    __shared__ int dlist[257];                 // rows for Dijkstra
    __shared__ int zcnt[257];                  // zero-cost displacement count

    // ---- warm local-XCD L2 with this batch's cost rows (~192 KB) ----
    {
        int total = N * M;
        for (int off = 4 * lane; off < total; off += 256) {
            float4 w = *reinterpret_cast<const float4*>(C + off);
            asm volatile("" :: "v"(w.x), "v"(w.y), "v"(w.z), "v"(w.w));
        }
    }

    for (int k = lane; k < N; k += 64) u[k + 1] = (double)rmv[b * N + k];
    for (int k = lane; k < 257; k += 64) { claim[k] = IINF; zcnt[k] = 0; }

    const int j_base = 4 * lane + 1;           // first owned pred-col (1-based)
    double v0, v1, v2, v3;
    int va0, va1, va2, va3;
    {
        const double* vb = vmin + (size_t)b * M + 4 * lane;
        v0 = vb[0]; v1 = vb[1]; v2 = vb[2]; v3 = vb[3];
        v_lds[4 * lane + 0] = v0; v_lds[4 * lane + 1] = v1;
        v_lds[4 * lane + 2] = v2; v_lds[4 * lane + 3] = v3;
        const int4 vg = *reinterpret_cast<const int4*>(
            varg + (size_t)b * M + 4 * lane);
        va0 = vg.x; va1 = vg.y; va2 = vg.z; va3 = vg.w;
    }
    __syncthreads();

    double m0, m1, m2, m3;
    int p0 = 0, p1 = 0, p2 = 0, p3 = 0;        // pred-col -> matched target
    int w0 = 0, w1 = 0, w2 = 0, w3 = 0;

    // ---- stage 1: column-side greedy via claims (rc==0 pairs exactly) ----
    atomicMin(&claim[va0], j_base + 0);
    atomicMin(&claim[va1], j_base + 1);
    atomicMin(&claim[va2], j_base + 2);
    atomicMin(&claim[va3], j_base + 3);
    __syncthreads();
    p0 = (claim[va0] == j_base + 0) ? va0 : 0;
    p1 = (claim[va1] == j_base + 1) ? va1 : 0;
    p2 = (claim[va2] == j_base + 2) ? va2 : 0;
    p3 = (claim[va3] == j_base + 3) ? va3 : 0;

    // rebuild claim[] as row -> OWNING column (losers cleared)
    __syncthreads();
    for (int k = lane; k < 257; k += 64) claim[k] = IINF;
    __syncthreads();
    if (p0) claim[p0] = j_base + 0;
    if (p1) claim[p1] = j_base + 1;
    if (p2) claim[p2] = j_base + 2;
    if (p3) claim[p3] = j_base + 3;
    __syncthreads();

    // unmatched-row list (ascending), ballot compaction
    int ucnt = 0;
    for (int c0 = 0; c0 < N; c0 += 64) {
        int t = c0 + lane + 1;
        bool un = (t <= N) && (claim[t] == IINF);
        unsigned long long mask = __ballot(un);
        int pos = ucnt + (int)__popcll(mask & ((1ULL << lane) - 1ULL));
        if (un) ulist[pos] = t;
        ucnt += (int)__popcll(mask);
    }
    __syncthreads();

    // ---- stage 1.5: reduction transfer (replacement form, exact f64) ----
    for (int c0 = 0; c0 < N; c0 += 64) {
        int t = c0 + lane + 1;
        if (t <= N && claim[t] != IINF) {
            int jt = claim[t] - 1;             // 0-based matched col
            const float* row = C + (size_t)(t - 1) * M;
            double mn = DINF;
            for (int jj = 0; jj < M; jj += 4) {
                float4 c4 = *reinterpret_cast<const float4*>(row + jj);
                double r0 = (double)c4.x - v_lds[jj];
                double r1 = (double)c4.y - v_lds[jj + 1];
                double r2 = (double)c4.z - v_lds[jj + 2];
                double r3 = (double)c4.w - v_lds[jj + 3];
                if (jj     != jt) mn = fmin(mn, r0);
                if (jj + 1 != jt) mn = fmin(mn, r1);
                if (jj + 2 != jt) mn = fmin(mn, r2);
                if (jj + 3 != jt) mn = fmin(mn, r3);
            }
            tmin[t] = mn;
        }
    }
    __syncthreads();
    for (int c0 = 0; c0 < N; c0 += 64) {
        int t = c0 + lane + 1;
        if (t <= N && claim[t] != IINF) {
            double mn = tmin[t];
            double dv = fmax(mn - u[t], 0.0);   // >= 0 up to 1e-16 dust
            u[t] = mn;                          // distinct t: race-free
            v_lds[claim[t] - 1] -= dv;          // distinct cols: race-free
        }
    }
    __syncthreads();
    v0 = v_lds[4 * lane + 0]; v1 = v_lds[4 * lane + 1];
    v2 = v_lds[4 * lane + 2]; v3 = v_lds[4 * lane + 3];

    // ---- stage 2: ARR with strict + zero-cost displacement (prefetched) ----
    int dcnt = 0;
    {
        int pi = 0, steps = 0;
        int i = (pi < ucnt) ? ulist[pi++] : 0;
        float4 r4 = *reinterpret_cast<const float4*>(
            C + (size_t)((i > 0 ? i : 1) - 1) * M + 4 * lane);
        while (i != 0) {
            ++steps;
            if (steps > 2048) {          // safety cap: dump rest to Dijkstra
                if (lane == 0) dlist[dcnt] = i;
                dcnt++;
                while (pi < ucnt) {
                    if (lane == 0) dlist[dcnt] = ulist[pi];
                    dcnt++; pi++;
                }
                break;
            }
            double rc0 = (double)r4.x - v0, rc1 = (double)r4.y - v1;
            double rc2 = (double)r4.z - v2, rc3 = (double)r4.w - v3;
            double l1 = rc0; int s1 = 0;
            if (rc1 < l1) { l1 = rc1; s1 = 1; }
            if (rc2 < l1) { l1 = rc2; s1 = 2; }
            if (rc3 < l1) { l1 = rc3; s1 = 3; }
            double l2 = DINF;
            if (s1 != 0) l2 = fmin(l2, rc0);
            if (s1 != 1) l2 = fmin(l2, rc1);
            if (s1 != 2) l2 = fmin(l2, rc2);
            if (s1 != 3) l2 = fmin(l2, rc3);

            double g1 = l1, g2 = l2;
            DPP_PAIR64_STAGE(g1, g2, 0x111);   // row_shr:1
            DPP_PAIR64_STAGE(g1, g2, 0x112);   // row_shr:2
            DPP_PAIR64_STAGE(g1, g2, 0x114);   // row_shr:4
            DPP_PAIR64_STAGE(g1, g2, 0x118);   // row_shr:8
            DPP_PAIR64_STAGE(g1, g2, 0x142);   // row_bcast:15
            DPP_PAIR64_STAGE(g1, g2, 0x143);   // row_bcast:31
            double u1 = readlane_f64(g1, 63);
            double u2 = readlane_f64(g2, 63);
            unsigned long long ball = __ballot(l1 == u1);
            int owner = __builtin_ctzll(ball);
            int pk = (j_base + s1) | (sel4(p0, p1, p2, p3, s1) << 9);
            pk = __builtin_amdgcn_readlane(pk, owner);
            int j1 = pk & 511, k = pk >> 9;

            // decide continuation + PREFETCH its row before the update tail
            bool strict = (u1 < u2);
            int zc_seen = zcnt[i];              // uniform read (pre-increment)
            bool zc = (!strict) && (k > 0) && (zc_seen < 4);
            int nexti;
            if (strict)       nexti = (k > 0) ? k : ((pi < ucnt) ? ulist[pi++] : 0);
            else if (k == 0)  nexti = (pi < ucnt) ? ulist[pi++] : 0;
            else if (zc)      nexti = k;
            else              nexti = (pi < ucnt) ? ulist[pi++] : 0;
            float4 r4n = *reinterpret_cast<const float4*>(
                C + (size_t)((nexti > 0 ? nexti : 1) - 1) * M + 4 * lane);

            if (strict) {
                // strict take: u[i]=u2, v[j1] -= (u2-u1) -> rc[i][j1]=0
                if (lane == 0) u[i] = u2;
                if (lane == ((j1 - 1) >> 2)) {
                    int s = (j1 - 1) & 3;
                    double dv = u2 - u1;
                    if (s == 0) { v0 -= dv; p0 = i; }
                    else if (s == 1) { v1 -= dv; p1 = i; }
                    else if (s == 2) { v2 -= dv; p2 = i; }
                    else { v3 -= dv; p3 = i; }
                }
            } else if (k == 0) {
                // tie, free column: assign, no v change
                if (lane == 0) u[i] = u1;
                if (lane == ((j1 - 1) >> 2)) {
                    int s = (j1 - 1) & 3;
                    if (s == 0) p0 = i;
                    else if (s == 1) p1 = i;
                    else if (s == 2) p2 = i;
                    else p3 = i;
                }
            } else if (zc) {
                // tie, occupied: zero-cost displacement (capped).
                if (lane == 0) { zcnt[i] = zc_seen + 1; u[i] = u1; }
                if (lane == ((j1 - 1) >> 2)) {
                    int s = (j1 - 1) & 3;
                    if (s == 0) p0 = i;
                    else if (s == 1) p1 = i;
                    else if (s == 2) p2 = i;
                    else p3 = i;
                }
            } else {
                // cap hit: defer to exact Dijkstra (u=u1 keeps rc>=0)
                if (lane == 0) { u[i] = u1; dlist[dcnt] = i; }
                dcnt++;
            }
            i = nexti; r4 = r4n;
        }
    }
    __syncthreads();

    // ---- stage 3: exact Dijkstra phases (next-phase prefetch) ----
    int tcur = (dcnt > 0) ? dlist[0] : 1;
    double ut_pf = u[tcur];
    float4 r4_pf = *reinterpret_cast<const float4*>(
        C + (size_t)(tcur - 1) * M + 4 * lane);
    for (int uk = 0; uk < dcnt; ++uk) {
        int t = tcur;
        double ut = ut_pf;          // u[t] at phase start (wave-uniform)
        float4 r4 = r4_pf;
        // prefetch NEXT phase's (row, u) — untouched during this phase
        {
            int tn = (uk + 1 < dcnt) ? dlist[uk + 1] : t;
            ut_pf = u[tn];
            r4_pf = *reinterpret_cast<const float4*>(
                C + (size_t)(tn - 1) * M + 4 * lane);
            tcur = tn;
        }

        m0 = DINF; m1 = DINF; m2 = DINF; m3 = DINF;
        int usedm = 0;
        double ur0 = 0, ur1 = 0, ur2 = 0, ur3 = 0;  // u of tree row per slot
        int tg0 = 0, tg1 = 0, tg2 = 0, tg3 = 0;     // tree-row target per slot
        int j0 = 0;                 // current pred-col (0 = virtual)
        int icur = t;               // row being scanned (p[j0]; p[0] = t)
        double u0 = ut;
        int jn;

        while (true) {
            // used[j0] = True; seed register copy of u[p[j0]]
            if (j0 != 0 && ((j0 - 1) >> 2) == lane) {
                int s = (j0 - 1) & 3;
                usedm |= 1 << s;
                if (s == 0) { ur0 = u0; tg0 = icur; }
                else if (s == 1) { ur1 = u0; tg1 = icur; }
                else if (s == 2) { ur2 = u0; tg2 = icur; }
                else { ur3 = u0; tg3 = icur; }
            }

            // cur = (c - u) - v ; strict < update (free cols only)
            double a0 = DINF, a1 = DINF, a2d = DINF, a3 = DINF;
            if (!(usedm & 1)) {
                double cur = ((double)r4.x - u0) - v0;
                if (cur < m0) { m0 = cur; w0 = j0; }
                a0 = m0;
            }
            if (!(usedm & 2)) {
                double cur = ((double)r4.y - u0) - v1;
                if (cur < m1) { m1 = cur; w1 = j0; }
                a1 = m1;
            }
            if (!(usedm & 4)) {
                double cur = ((double)r4.z - u0) - v2;
                if (cur < m2) { m2 = cur; w2 = j0; }
                a2d = m2;
            }
            if (!(usedm & 8)) {
                double cur = ((double)r4.w - u0) - v3;
                if (cur < m3) { m3 = cur; w3 = j0; }
                a3 = m3;
            }

            // lane-local (min, smallest slot)
            double av = a0; int sa = 0;
            if (a1 < av)  { av = a1;  sa = 1; }
            if (a2d < av) { av = a2d; sa = 2; }
            if (a3 < av)  { av = a3;  sa = 3; }

            // wave min via f64 DPP ladder; lane 63 holds the result
            double wv_ = av;
            DPP_FMIN64_STAGE(wv_, 0x111);   // row_shr:1
            DPP_FMIN64_STAGE(wv_, 0x112);   // row_shr:2
            DPP_FMIN64_STAGE(wv_, 0x114);   // row_shr:4
            DPP_FMIN64_STAGE(wv_, 0x118);   // row_shr:8
            DPP_FMIN64_STAGE(wv_, 0x142);   // row_bcast:15
            DPP_FMIN64_STAGE(wv_, 0x143);   // row_bcast:31
            double delta = readlane_f64(wv_, 63);

            unsigned long long ball = __ballot(av == delta);
            int owner = __builtin_ctzll(ball);   // lowest lane = smallest col
            int pk = (j_base + sa) | (sel4(p0, p1, p2, p3, sa) << 9);
            pk = __builtin_amdgcn_readlane(pk, owner);
            int jn_ = pk & 511, pjn = pk >> 9;

            // early reads for next iteration (u has NO writes during a phase)
            int nxt = (pjn > 0) ? pjn : t;
            double u_next = u[nxt];
            float4 r4n = *reinterpret_cast<const float4*>(
                C + (size_t)(nxt - 1) * M + 4 * lane);

            // per-iteration dual/minv updates (register-resident)
            if (usedm & 1) { ur0 += delta; v0 -= delta; } else m0 -= delta;
            if (usedm & 2) { ur1 += delta; v1 -= delta; } else m1 -= delta;
            if (usedm & 4) { ur2 += delta; v2 -= delta; } else m2 -= delta;
            if (usedm & 8) { ur3 += delta; v3 -= delta; } else m3 -= delta;
            ut += delta;                       // virtual column: p[0] = t

            jn = jn_;
            if (pjn == 0) break;
            j0 = jn_; u0 = u_next; r4 = r4n; icur = pjn;
        }

        // phase-end u writeback (distinct targets per used column: race-free)
        if (usedm & 1) u[tg0] = ur0;
        if (usedm & 2) u[tg1] = ur1;
        if (usedm & 4) u[tg2] = ur2;
        if (usedm & 8) u[tg3] = ur3;
        if (lane == 0) u[t] = ut;

        // augment: stream p[j_k] = p_old[j_{k+1}] one step behind.
        int jj = jn, prev = 0;
        while (true) {
            int idx = jj - 1;
            int o = idx >> 2, s = idx & 3;
            int packv = sel4(w0, w1, w2, w3, s) |
                        (sel4(p0, p1, p2, p3, s) << 9);
            packv = __builtin_amdgcn_readlane(packv, o);
            int wv = packv & 511, pold = packv >> 9;
            if (prev != 0) {
                int pi = prev - 1;
                if (lane == (pi >> 2)) {
                    int sp = pi & 3;
                    if (sp == 0) p0 = pold;
                    else if (sp == 1) p1 = pold;
                    else if (sp == 2) p2 = pold;
                    else p3 = pold;
                }
            }
            if (wv == 0) {
                if (lane == o) {
                    if (s == 0) p0 = t;
                    else if (s == 1) p1 = t;
                    else if (s == 2) p2 = t;
                    else p3 = t;
                }
                break;
            }
            prev = jj; jj = wv;
        }
    }

    // matched sums over real pairs: pred-col j (owned) matched to target p[j]
    double sm = 0.0, ss = 0.0, sb = 0.0;
#pragma unroll
    for (int s = 0; s < 4; ++s) {
        int pt = sel4(p0, p1, p2, p3, s);
        if (pt != 0) {
            int r = j_base + s - 1;   // pred index
            int c = pt - 1;           // target index
            sm += (double)C[(size_t)c * M + r];
            sb += (double)boxc[((size_t)b * M + r) * N + c];
            ss += (double)fmaxf(0.0f, t_score[b * N + c] - p_score[b * M + r]);
        }
    }
#pragma unroll
    for (int off = 1; off < 64; off <<= 1) {
        sm += __shfl_xor(sm, off, 64);
        ss += __shfl_xor(ss, off, 64);
        sb += __shfl_xor(sb, off, 64);
    }
    if (lane == 0) {
        out[0 * B + b] = (float)(sm / N);
        out[1 * B + b] = (float)(ss / N);
        out[2 * B + b] = (float)(sb / N);
    }
}

extern "C" void kernel_launch(void* const* d_in, const int* in_sizes, int n_in,
                              void* d_out, int out_size, void* d_ws, size_t ws_size,
                              hipStream_t stream) {
    int B = out_size / 3;                 // out is [3, B]
    int M = in_sizes[1] / B;              // pred_score [B, M]
    int N = in_sizes[3] / B;              // target_score [B, N]

    const float* p_box   = (const float*)d_in[0];
    const float* p_score = (const float*)d_in[1];
    const float* t_box   = (const float*)d_in[2];
    const float* t_score = (const float*)d_in[3];
    float* out = (float*)d_out;

    float*  Ct   = (float*)d_ws;                      // [B, N, M]
    float*  boxc = Ct + (size_t)B * N * M;            // [B, M, N]
    float*  rmv  = boxc + (size_t)B * M * N;          // [B, N]
    double* vmin = (double*)(rmv + (size_t)B * N);    // [B, M] (8B aligned)
    int*    varg = (int*)(vmin + (size_t)B * M);      // [B, M]

    int total = B * M * N;
    cost_kernel<<<(total + 255) / 256, 256, 0, stream>>>(
        p_box, p_score, t_box, t_score, Ct, boxc, B, M, N);
    rowmin_kernel<<<B * N, 64, 0, stream>>>(Ct, rmv, M);
    colmin_kernel<<<B, 256, 0, stream>>>(Ct, rmv, vmin, varg, M, N);
    hungarian_rect<<<B, 64, 0, stream>>>(
        Ct, boxc, p_score, t_score, rmv, vmin, varg, out, B, M, N);
}

// Round 15
// 229.633 us; speedup vs baseline: 1.2162x; 1.2162x over previous
//
#include <hip/hip_runtime.h>
#include <cmath>

#define MAXV 8

// ---------------------------------------------------------------------------
// Kernel 1: cost matrices for the RECTANGULAR problem (no padding).
//   Ct[b][n][m]  = score_cost + giou_cost   (transposed cost, coalesced rows)
//   boxc[b][m][n] = giou_cost
// Math mirrors the reference f32 op order exactly.
// ---------------------------------------------------------------------------
__global__ __launch_bounds__(256) void cost_kernel(
    const float* __restrict__ p_box, const float* __restrict__ p_score,
    const float* __restrict__ t_box, const float* __restrict__ t_score,
    float* __restrict__ Ct, float* __restrict__ boxc,
    int B, int M, int N)
{
    int g = blockIdx.x * 256 + threadIdx.x;
    int total = B * M * N;
    if (g >= total) return;
    int b = g / (M * N);
    int rem = g - b * M * N;
    int n = rem / M;
    int m = rem - n * M;

    const float* bp = p_box + ((size_t)b * M + m) * 5;
    const float* bt = t_box + ((size_t)b * N + n) * 5;
    float pcx = bp[0], pcy = bp[1], pw = bp[2], ph = bp[3], pth = bp[4];
    float tcx = bt[0], tcy = bt[1], tw = bt[2], th = bt[3], tth = bt[4];

    float pc = cosf(pth), ps = sinf(pth);
    float tc = cosf(tth), ts = sinf(tth);

    const float DX[4] = {-0.5f, 0.5f, 0.5f, -0.5f};
    const float DY[4] = {-0.5f, -0.5f, 0.5f, 0.5f};
    float cpx[4], cpy[4], ctx[4], cty[4];
#pragma unroll
    for (int k = 0; k < 4; k++) {
        float dx = DX[k] * pw, dy = DY[k] * ph;
        cpx[k] = pcx + dx * pc - dy * ps;
        cpy[k] = pcy + dx * ps + dy * pc;
        float dx2 = DX[k] * tw, dy2 = DY[k] * th;
        ctx[k] = tcx + dx2 * tc - dy2 * ts;
        cty[k] = tcy + dx2 * ts + dy2 * tc;
    }

    float px[MAXV], py[MAXV];
#pragma unroll
    for (int k = 0; k < MAXV; k++) {
        px[k] = (k < 4) ? cpx[k] : 0.0f;
        py[k] = (k < 4) ? cpy[k] : 0.0f;
    }
    int cnt = 4;

#pragma unroll
    for (int e = 0; e < 4; e++) {
        float ax = ctx[e], ay = cty[e];
        float bx2 = ctx[(e + 1) & 3], by2 = cty[(e + 1) & 3];
        float dx = bx2 - ax, dy = by2 - ay;
        float qx[MAXV], qy[MAXV];
#pragma unroll
        for (int k = 0; k < MAXV; k++) { qx[k] = 0.0f; qy[k] = 0.0f; }
        int nc = 0;
#pragma unroll
        for (int i = 0; i < MAXV; i++) {
            if (i < cnt) {
                bool wrap = !(i + 1 < cnt);
                float nx = wrap ? px[0] : px[(i + 1) & 7];
                float ny = wrap ? py[0] : py[(i + 1) & 7];
                float sc = dx * (py[i] - ay) - dy * (px[i] - ax);
                float sn = dx * (ny - ay) - dy * (nx - ax);
                bool inc = (sc >= 0.0f), inn = (sn >= 0.0f);
                float den = sc - sn;
                if (!(fabsf(den) > 1e-9f)) den = 1e-9f;
                float t = sc / den;
                float ix = px[i] + t * (nx - px[i]);
                float iy = py[i] + t * (ny - py[i]);
                if (inc) {
                    if (nc < MAXV) { qx[nc] = px[i]; qy[nc] = py[i]; }
                    nc++;
                }
                if (inc != inn) {
                    if (nc < MAXV) { qx[nc] = ix; qy[nc] = iy; }
                    nc++;
                }
            }
        }
        cnt = (nc > MAXV) ? MAXV : nc;
#pragma unroll
        for (int k = 0; k < MAXV; k++) {
            px[k] = (k < cnt) ? qx[k] : 0.0f;
            py[k] = (k < cnt) ? qy[k] : 0.0f;
        }
    }

    float a2 = 0.0f;
#pragma unroll
    for (int i = 0; i < MAXV; i++) {
        if (i < cnt) {
            bool wrap = !(i + 1 < cnt);
            float nx = wrap ? px[0] : px[(i + 1) & 7];
            float ny = wrap ? py[0] : py[(i + 1) & 7];
            a2 += px[i] * ny - nx * py[i];
        }
    }
    float inter = 0.5f * fabsf(a2);

    float uni = tw * th + pw * ph - inter;

    float xmin = ctx[0], xmax = ctx[0], ymin = cty[0], ymax = cty[0];
#pragma unroll
    for (int k = 1; k < 4; k++) {
        xmin = fminf(xmin, ctx[k]); xmax = fmaxf(xmax, ctx[k]);
        ymin = fminf(ymin, cty[k]); ymax = fmaxf(ymax, cty[k]);
    }
#pragma unroll
    for (int k = 0; k < 4; k++) {
        xmin = fminf(xmin, cpx[k]); xmax = fmaxf(xmax, cpx[k]);
        ymin = fminf(ymin, cpy[k]); ymax = fmaxf(ymax, cpy[k]);
    }
    float enc = (xmax - xmin) * (ymax - ymin);

    float giou = inter / uni - (enc - uni) / enc;
    float bc = 1.0f - giou;
    float scst = fmaxf(0.0f, t_score[b * N + n] - p_score[b * M + m]);

    Ct[((size_t)b * N + n) * M + m] = scst + bc;
    boxc[((size_t)b * M + m) * N + n] = bc;
}

// ---------------------------------------------------------------------------
// Kernel 1.5: per-target-row min over the M pred columns (u init).
// ---------------------------------------------------------------------------
__global__ __launch_bounds__(64) void rowmin_kernel(
    const float* __restrict__ Ct, float* __restrict__ rmv, int M)
{
    int bt = blockIdx.x;
    int lane = threadIdx.x;
    const float* row = Ct + (size_t)bt * M;

    float bv = 1e30f;
    for (int c = 4 * lane; c < M; c += 256) {
        float4 v = *reinterpret_cast<const float4*>(row + c);
        bv = fminf(bv, fminf(fminf(v.x, v.y), fminf(v.z, v.w)));
    }
#pragma unroll
    for (int off = 1; off < 64; off <<= 1)
        bv = fminf(bv, __shfl_xor(bv, off, 64));
    if (lane == 0) rmv[bt] = bv;
}

// ---------------------------------------------------------------------------
// Kernel 1.6: per-column (min, first argmin row) of the u-reduced matrix.
// ---------------------------------------------------------------------------
__global__ __launch_bounds__(256) void colmin_kernel(
    const float* __restrict__ Ct, const float* __restrict__ rmv,
    float* __restrict__ vmin, int* __restrict__ varg, int M, int N)
{
    int b = blockIdx.x;
    const float* Cb = Ct + (size_t)b * N * M;
    const float* rb = rmv + (size_t)b * N;
    for (int j = threadIdx.x; j < M; j += blockDim.x) {
        float bv = 1e30f; int bt = 0;
        for (int t = 0; t < N; ++t) {
            float val = Cb[(size_t)t * M + j] - rb[t];
            if (val < bv) { bv = val; bt = t; }
        }
        vmin[(size_t)b * M + j] = bv;
        varg[(size_t)b * M + j] = bt + 1;   // 1-based target
    }
}

// ---------------------------------------------------------------------------
// Kernel 2: rectangular JV Hungarian, single wave per batch, four stages:
//  (1) two-sided-reduction init: u[t]=rowmin, v[j]=colmin of reduced matrix
//      (both computed by parallel kernels); column-side greedy: col j claims
//      its argmin row (rc==0 exactly in f32), conflicts -> smallest j via
//      LDS atomicMin. CS + feasibility hold exactly.
//  (2) augmenting row reduction (exact JV ARR) for leftover rows.
//  (3) e-maxx Dijkstra phases for ARR-deferred rows.
//  (4) matched sums.
// ---------------------------------------------------------------------------
__device__ __forceinline__ int sel4(int a0, int a1, int a2, int a3, int s) {
    return s == 0 ? a0 : (s == 1 ? a1 : (s == 2 ? a2 : a3));
}

// val = fminf(val, dpp_neighbor(val)); invalid lanes contribute +inf.
#define DPP_FMIN32_STAGE(val, CTRL) do {                                      \
    int _o = __builtin_amdgcn_update_dpp(0x7F800000,                          \
                 __float_as_int(val), CTRL, 0xf, 0xf, false);                 \
    (val) = fminf((val), __int_as_float(_o));                                 \
} while (0)

// paired (min1,min2) reduction stage; disjoint lane-set combine.
#define DPP_PAIR_STAGE(g1, g2, CTRL) do {                                     \
    int _b1 = __builtin_amdgcn_update_dpp(0x7F800000,                         \
                  __float_as_int(g1), CTRL, 0xf, 0xf, false);                 \
    int _b2 = __builtin_amdgcn_update_dpp(0x7F800000,                         \
                  __float_as_int(g2), CTRL, 0xf, 0xf, false);                 \
    float _o1 = __int_as_float(_b1), _o2 = __int_as_float(_b2);               \
    float _n2 = fminf(fmaxf((g1), _o1), fminf((g2), _o2));                    \
    (g1) = fminf((g1), _o1);                                                  \
    (g2) = _n2;                                                               \
} while (0)

__global__ __launch_bounds__(64) void hungarian_rect(
    const float* __restrict__ Ct, const float* __restrict__ boxc,
    const float* __restrict__ p_score, const float* __restrict__ t_score,
    const float* __restrict__ rmv, const float* __restrict__ vmin,
    const int* __restrict__ varg,
    float* __restrict__ out, int B, int M, int N)
{
    const float FINF = 1e30f;
    const int IINF = 0x7fffffff;
    int b = blockIdx.x;
    int lane = threadIdx.x;
    const float* C = Ct + (size_t)b * N * M;   // [N][M] rows contiguous

    __shared__ float u[257];                   // dual u, target 1..N
    __shared__ int claim[257];                 // row -> smallest claiming col
    __shared__ int ulist[257];                 // rows for ARR
    __shared__ int dlist[257];                 // rows for Dijkstra

    // ---- warm local-XCD L2 with this batch's cost rows (~192 KB) ----
    {
        int total = N * M;
        for (int off = 4 * lane; off < total; off += 256) {
            float4 w = *reinterpret_cast<const float4*>(C + off);
            asm volatile("" :: "v"(w.x), "v"(w.y), "v"(w.z), "v"(w.w));
        }
    }

    for (int k = lane; k < N; k += 64) u[k + 1] = rmv[b * N + k];
    for (int k = lane; k < 257; k += 64) claim[k] = IINF;
    __syncthreads();

    const int j_base = 4 * lane + 1;           // first owned pred-col (1-based)
    // v duals from colmin kernel
    float v0, v1, v2, v3;
    int va0, va1, va2, va3;
    {
        const float4 vm = *reinterpret_cast<const float4*>(
            vmin + (size_t)b * M + 4 * lane);
        v0 = vm.x; v1 = vm.y; v2 = vm.z; v3 = vm.w;
        const int4 vg = *reinterpret_cast<const int4*>(
            varg + (size_t)b * M + 4 * lane);
        va0 = vg.x; va1 = vg.y; va2 = vg.z; va3 = vg.w;
    }

    float m0, m1, m2, m3;
    int p0 = 0, p1 = 0, p2 = 0, p3 = 0;        // pred-col -> matched target
    int w0 = 0, w1 = 0, w2 = 0, w3 = 0;

    // ---- stage 1: column-side greedy via claims (rc==0 pairs exactly) ----
    atomicMin(&claim[va0], j_base + 0);
    atomicMin(&claim[va1], j_base + 1);
    atomicMin(&claim[va2], j_base + 2);
    atomicMin(&claim[va3], j_base + 3);
    __syncthreads();
    p0 = (claim[va0] == j_base + 0) ? va0 : 0;
    p1 = (claim[va1] == j_base + 1) ? va1 : 0;
    p2 = (claim[va2] == j_base + 2) ? va2 : 0;
    p3 = (claim[va3] == j_base + 3) ? va3 : 0;

    // unmatched-row list (ascending), ballot compaction
    int ucnt = 0;
    for (int c0 = 0; c0 < N; c0 += 64) {
        int t = c0 + lane + 1;
        bool un = (t <= N) && (claim[t] == IINF);
        unsigned long long mask = __ballot(un);
        int pos = ucnt + (int)__popcll(mask & ((1ULL << lane) - 1ULL));
        if (un) ulist[pos] = t;
        ucnt += (int)__popcll(mask);
    }
    __syncthreads();

    // ---- stage 2: augmenting row reduction (exact JV ARR) ----
    int dcnt = 0;
    {
        int pi = 0, steps = 0;
        int i = (pi < ucnt) ? ulist[pi++] : 0;
        while (i != 0) {
            ++steps;
            if (steps > 2048) {          // safety cap: dump rest to Dijkstra
                if (lane == 0) dlist[dcnt] = i;
                dcnt++;
                while (pi < ucnt) {
                    if (lane == 0) dlist[dcnt] = ulist[pi];
                    dcnt++; pi++;
                }
                break;
            }
            float4 r4 = *reinterpret_cast<const float4*>(
                C + (size_t)(i - 1) * M + 4 * lane);
            float rc0 = r4.x - v0, rc1 = r4.y - v1;
            float rc2 = r4.z - v2, rc3 = r4.w - v3;
            float l1 = rc0; int s1 = 0;
            if (rc1 < l1) { l1 = rc1; s1 = 1; }
            if (rc2 < l1) { l1 = rc2; s1 = 2; }
            if (rc3 < l1) { l1 = rc3; s1 = 3; }
            float l2 = FINF;
            if (s1 != 0) l2 = fminf(l2, rc0);
            if (s1 != 1) l2 = fminf(l2, rc1);
            if (s1 != 2) l2 = fminf(l2, rc2);
            if (s1 != 3) l2 = fminf(l2, rc3);

            float g1 = l1, g2 = l2;
            DPP_PAIR_STAGE(g1, g2, 0x111);   // row_shr:1
            DPP_PAIR_STAGE(g1, g2, 0x112);   // row_shr:2
            DPP_PAIR_STAGE(g1, g2, 0x114);   // row_shr:4
            DPP_PAIR_STAGE(g1, g2, 0x118);   // row_shr:8
            DPP_PAIR_STAGE(g1, g2, 0x142);   // row_bcast:15
            DPP_PAIR_STAGE(g1, g2, 0x143);   // row_bcast:31
            float u1 = __int_as_float(
                __builtin_amdgcn_readlane(__float_as_int(g1), 63));
            float u2 = __int_as_float(
                __builtin_amdgcn_readlane(__float_as_int(g2), 63));
            unsigned long long ball = __ballot(l1 == u1);
            int owner = __builtin_ctzll(ball);
            int pk = (j_base + s1) | (sel4(p0, p1, p2, p3, s1) << 9);
            pk = __builtin_amdgcn_readlane(pk, owner);
            int j1 = pk & 511, k = pk >> 9;

            if (u1 < u2) {
                // take j1: u[i]=u2, v[j1] -= (u2-u1) -> rc[i][j1]=0 exact
                if (lane == 0) u[i] = u2;
                if (lane == ((j1 - 1) >> 2)) {
                    int s = (j1 - 1) & 3;
                    float dv = u2 - u1;
                    if (s == 0) { v0 -= dv; p0 = i; }
                    else if (s == 1) { v1 -= dv; p1 = i; }
                    else if (s == 2) { v2 -= dv; p2 = i; }
                    else { v3 -= dv; p3 = i; }
                }
                if (k > 0) { i = k; continue; }   // displaced row continues
            } else if (k == 0) {
                // exact tie but column free: assign, no v change
                if (lane == 0) u[i] = u1;
                if (lane == ((j1 - 1) >> 2)) {
                    int s = (j1 - 1) & 3;
                    if (s == 0) p0 = i;
                    else if (s == 1) p1 = i;
                    else if (s == 2) p2 = i;
                    else p3 = i;
                }
            } else {
                // exact tie on occupied column: defer to Dijkstra
                if (lane == 0) { u[i] = u1; dlist[dcnt] = i; }
                dcnt++;
            }
            i = (pi < ucnt) ? ulist[pi++] : 0;
        }
    }
    __syncthreads();

    // ---- stage 3: exact Dijkstra phases for deferred targets ----
    for (int uk = 0; uk < dcnt; ++uk) {
        int t = dlist[uk];
        m0 = FINF; m1 = FINF; m2 = FINF; m3 = FINF;
        int usedm = 0;
        float ur0 = 0, ur1 = 0, ur2 = 0, ur3 = 0;   // u of tree row per slot
        int tg0 = 0, tg1 = 0, tg2 = 0, tg3 = 0;     // tree-row target per slot
        int j0 = 0;                 // current pred-col (0 = virtual)
        int icur = t;               // row being scanned (p[j0]; p[0] = t)
        float ut = u[t];            // u[t], tracked in-register (wave-uniform)
        float u0 = ut;
        float4 r4 = *reinterpret_cast<const float4*>(
            C + (size_t)(t - 1) * M + 4 * lane);
        int jn;

        while (true) {
            // used[j0] = True; seed register copy of u[p[j0]]
            if (j0 != 0 && ((j0 - 1) >> 2) == lane) {
                int s = (j0 - 1) & 3;
                usedm |= 1 << s;
                if (s == 0) { ur0 = u0; tg0 = icur; }
                else if (s == 1) { ur1 = u0; tg1 = icur; }
                else if (s == 2) { ur2 = u0; tg2 = icur; }
                else { ur3 = u0; tg3 = icur; }
            }

            // cur = (c - u) - v ; strict < update (free cols only)
            float a0 = FINF, a1 = FINF, a2f = FINF, a3 = FINF;
            if (!(usedm & 1)) {
                float cur = (r4.x - u0) - v0;
                if (cur < m0) { m0 = cur; w0 = j0; }
                a0 = m0;
            }
            if (!(usedm & 2)) {
                float cur = (r4.y - u0) - v1;
                if (cur < m1) { m1 = cur; w1 = j0; }
                a1 = m1;
            }
            if (!(usedm & 4)) {
                float cur = (r4.z - u0) - v2;
                if (cur < m2) { m2 = cur; w2 = j0; }
                a2f = m2;
            }
            if (!(usedm & 8)) {
                float cur = (r4.w - u0) - v3;
                if (cur < m3) { m3 = cur; w3 = j0; }
                a3 = m3;
            }

            // lane-local (min, smallest slot)
            float av = a0; int sa = 0;
            if (a1 < av)  { av = a1;  sa = 1; }
            if (a2f < av) { av = a2f; sa = 2; }
            if (a3 < av)  { av = a3;  sa = 3; }

            // wave min via v_min_f32 DPP ladder; lane 63 holds the result
            float wv_ = av;
            DPP_FMIN32_STAGE(wv_, 0x111);   // row_shr:1
            DPP_FMIN32_STAGE(wv_, 0x112);   // row_shr:2
            DPP_FMIN32_STAGE(wv_, 0x114);   // row_shr:4
            DPP_FMIN32_STAGE(wv_, 0x118);   // row_shr:8
            DPP_FMIN32_STAGE(wv_, 0x142);   // row_bcast:15
            DPP_FMIN32_STAGE(wv_, 0x143);   // row_bcast:31
            float delta = __int_as_float(
                __builtin_amdgcn_readlane(__float_as_int(wv_), 63));

            unsigned long long ball = __ballot(av == delta);
            int owner = __builtin_ctzll(ball);   // lowest lane = smallest col
            int pk = (j_base + sa) | (sel4(p0, p1, p2, p3, sa) << 9);
            pk = __builtin_amdgcn_readlane(pk, owner);
            int jn_ = pk & 511, pjn = pk >> 9;

            // early reads for next iteration (u has NO writes during a phase)
            int nxt = (pjn > 0) ? pjn : t;
            float u_next = u[nxt];
            float4 r4n = *reinterpret_cast<const float4*>(
                C + (size_t)(nxt - 1) * M + 4 * lane);

            // per-iteration dual/minv updates (register-resident)
            if (usedm & 1) { ur0 += delta; v0 -= delta; } else m0 -= delta;
            if (usedm & 2) { ur1 += delta; v1 -= delta; } else m1 -= delta;
            if (usedm & 4) { ur2 += delta; v2 -= delta; } else m2 -= delta;
            if (usedm & 8) { ur3 += delta; v3 -= delta; } else m3 -= delta;
            ut += delta;                       // virtual column: p[0] = t

            jn = jn_;
            if (pjn == 0) break;
            j0 = jn_; u0 = u_next; r4 = r4n; icur = pjn;
        }

        // phase-end u writeback (distinct targets per used column: race-free)
        if (usedm & 1) u[tg0] = ur0;
        if (usedm & 2) u[tg1] = ur1;
        if (usedm & 4) u[tg2] = ur2;
        if (usedm & 8) u[tg3] = ur3;
        if (lane == 0) u[t] = ut;

        // augment: stream p[j_k] = p_old[j_{k+1}] one step behind the
        // traversal; one readlane per step (packed way|p).
        int jj = jn, prev = 0;
        while (true) {
            int idx = jj - 1;
            int o = idx >> 2, s = idx & 3;
            int packv = sel4(w0, w1, w2, w3, s) |
                        (sel4(p0, p1, p2, p3, s) << 9);
            packv = __builtin_amdgcn_readlane(packv, o);
            int wv = packv & 511, pold = packv >> 9;
            if (prev != 0) {
                int pi = prev - 1;
                if (lane == (pi >> 2)) {
                    int sp = pi & 3;
                    if (sp == 0) p0 = pold;
                    else if (sp == 1) p1 = pold;
                    else if (sp == 2) p2 = pold;
                    else p3 = pold;
                }
            }
            if (wv == 0) {
                if (lane == o) {
                    if (s == 0) p0 = t;
                    else if (s == 1) p1 = t;
                    else if (s == 2) p2 = t;
                    else p3 = t;
                }
                break;
            }
            prev = jj; jj = wv;
        }
    }

    // matched sums over real pairs: pred-col j (owned) matched to target p[j]
    double sm = 0.0, ss = 0.0, sb = 0.0;
#pragma unroll
    for (int s = 0; s < 4; ++s) {
        int pt = sel4(p0, p1, p2, p3, s);
        if (pt != 0) {
            int r = j_base + s - 1;   // pred index
            int c = pt - 1;           // target index
            sm += (double)C[(size_t)c * M + r];
            sb += (double)boxc[((size_t)b * M + r) * N + c];
            ss += (double)fmaxf(0.0f, t_score[b * N + c] - p_score[b * M + r]);
        }
    }
#pragma unroll
    for (int off = 1; off < 64; off <<= 1) {
        sm += __shfl_xor(sm, off, 64);
        ss += __shfl_xor(ss, off, 64);
        sb += __shfl_xor(sb, off, 64);
    }
    if (lane == 0) {
        out[0 * B + b] = (float)(sm / N);
        out[1 * B + b] = (float)(ss / N);
        out[2 * B + b] = (float)(sb / N);
    }
}

extern "C" void kernel_launch(void* const* d_in, const int* in_sizes, int n_in,
                              void* d_out, int out_size, void* d_ws, size_t ws_size,
                              hipStream_t stream) {
    int B = out_size / 3;                 // out is [3, B]
    int M = in_sizes[1] / B;              // pred_score [B, M]
    int N = in_sizes[3] / B;              // target_score [B, N]

    const float* p_box   = (const float*)d_in[0];
    const float* p_score = (const float*)d_in[1];
    const float* t_box   = (const float*)d_in[2];
    const float* t_score = (const float*)d_in[3];
    float* out = (float*)d_out;

    float* Ct   = (float*)d_ws;                       // [B, N, M]
    float* boxc = Ct + (size_t)B * N * M;             // [B, M, N]
    float* rmv  = boxc + (size_t)B * M * N;           // [B, N]
    float* vmin = rmv + (size_t)B * N;                // [B, M]
    int*   varg = (int*)(vmin + (size_t)B * M);       // [B, M]

    int total = B * M * N;
    cost_kernel<<<(total + 255) / 256, 256, 0, stream>>>(
        p_box, p_score, t_box, t_score, Ct, boxc, B, M, N);
    rowmin_kernel<<<B * N, 64, 0, stream>>>(Ct, rmv, M);
    colmin_kernel<<<B, 256, 0, stream>>>(Ct, rmv, vmin, varg, M, N);
    hungarian_rect<<<B, 64, 0, stream>>>(
        Ct, boxc, p_score, t_score, rmv, vmin, varg, out, B, M, N);
}